// Round 4
// baseline (3367.108 us; speedup 1.0000x reference)
//
#include <hip/hip_runtime.h>

// DecoderGRU persistent-kernel version.
// h_{t+1} = GRUCell(h_t, h_t), 64 steps. Combined gates: r,z use (W_ih+W_hh),
// n keeps i_n / h_n -> [512,1024]x[1024,4096] bf16 GEMM per step.
// One persistent kernel: 256 blocks (1/CU), 512 threads (8 waves = gate x K-half).
// Weights live in VGPRs (128/wave) for the whole sequence; h lives in VGPRs;
// only the bf16 A (h) slab flows global->LDS->MFMA each step.
// Rows are independent => per-rb flag barriers (32 blocks, XCD-local with rb=bid&7).

typedef float  f32x4 __attribute__((ext_vector_type(4)));
typedef __bf16 bf16x8 __attribute__((ext_vector_type(8)));
typedef unsigned short u16x8 __attribute__((ext_vector_type(8)));
typedef unsigned short u16x4 __attribute__((ext_vector_type(4)));

#define GPTR(p) ((const __attribute__((address_space(1))) unsigned int*)(p))
#define LPTR(p) ((__attribute__((address_space(3))) unsigned int*)(p))

// ws layout (bytes)
#define WB_OFF   0u            // 8 MB fragment-packed bf16 weights
#define BIAS_OFF 8388608u      // 16 KB combined biases [4][1024]
#define A0_OFF   8404992u      // 1 MB fragment-packed bf16 h (ping)
#define A1_OFF   9453568u      // 1 MB (pong)
#define FLAG_OFF 10502144u     // 4 KB flags [8 rb][128]

__device__ __forceinline__ unsigned short f2bf(float f){
  unsigned int u = __builtin_bit_cast(unsigned int, f);
  u = (u + 0x7FFFu + ((u >> 16) & 1u)) >> 16;
  return (unsigned short)u;
}

// ---------------------------------------------------------------------------
// Prologue 1: combined weights -> fragment-packed bf16 WB.
// Fragment (j,g,kk,n): 64 lanes x 16B at (((j*4+g)*32+kk)*2+n)*1024 + lane*16.
// Element (gate g, h-col c, k): j=c>>5, n=(c>>4)&1, lane=(c&15)+((k>>3)&3)*16,
// kk=k>>5, e=k&7.  gates: 0=r(ih+hh) 1=z(ih+hh) 2=i_n(ih) 3=h_n(hh).
// ---------------------------------------------------------------------------
extern "C" __global__ void gru_weights(const float* __restrict__ wih,
                                       const float* __restrict__ whh,
                                       char* __restrict__ WB){
  int gt  = blockIdx.x * 256 + threadIdx.x;   // 524288 threads
  int k0  = (gt & 127) << 3;                  // 8 k's per thread
  int gid = gt >> 7;
  int g   = gid >> 10, c = gid & 1023;
  int srow = (g < 2) ? g * 1024 + c : 2048 + c;
  const float* pa = ((g == 3) ? whh : wih) + srow * 1024 + k0;
  f32x4 v0 = ((const f32x4*)pa)[0];
  f32x4 v1 = ((const f32x4*)pa)[1];
  if (g < 2){
    const float* pb = whh + srow * 1024 + k0;
    v0 += ((const f32x4*)pb)[0];
    v1 += ((const f32x4*)pb)[1];
  }
  u16x8 o;
  #pragma unroll
  for (int e = 0; e < 4; e++){ o[e] = f2bf(v0[e]); o[4 + e] = f2bf(v1[e]); }
  int j = c >> 5, n = (c >> 4) & 1, kk = k0 >> 5;
  int lane = (c & 15) + ((k0 >> 3) & 3) * 16;
  int addr = (((j * 4 + g) * 32 + kk) * 2 + n) * 1024 + lane * 16;
  *(u16x8*)(WB + addr) = o;
}

// ---------------------------------------------------------------------------
// Prologue 2: initial h -> fragment-packed bf16 A0; combined biases; zero flags.
// A frag (rb, chunk c, s, p, m): fragidx = rb*128 + ((c*2+s)*2+p)*4 + m,
// where k-slice kk(of h-col) = s*16 + c*2 + p.
// ---------------------------------------------------------------------------
extern "C" __global__ void gru_init(const float* __restrict__ hidden,
                                    const float* __restrict__ bih,
                                    const float* __restrict__ bhh,
                                    char* __restrict__ A0,
                                    float* __restrict__ bias,
                                    int* __restrict__ flag){
  int gt = blockIdx.x * 256 + threadIdx.x;    // 65536 threads, 8 elems each
  int e0 = gt * 8;
  int r  = e0 >> 10, c0 = e0 & 1023;          // row, h-col base (8-aligned)
  f32x4 v0 = ((const f32x4*)(hidden + e0))[0];
  f32x4 v1 = ((const f32x4*)(hidden + e0))[1];
  u16x8 o;
  #pragma unroll
  for (int e = 0; e < 4; e++){ o[e] = f2bf(v0[e]); o[4 + e] = f2bf(v1[e]); }
  int rb = r >> 6, lr = r & 63, m = lr >> 4;
  int kk = c0 >> 5, s = kk >> 4, cp = (kk & 15) >> 1, p = kk & 1;
  int fragidx = rb * 128 + ((cp * 2 + s) * 2 + p) * 4 + m;
  int lane = (r & 15) + ((c0 >> 3) & 3) * 16;
  *(u16x8*)(A0 + fragidx * 1024 + lane * 16) = o;
  if (blockIdx.x < 16){
    int bi = blockIdx.x * 256 + threadIdx.x;  // 4096 bias entries
    int g = bi >> 10, c = bi & 1023;
    float v = (g == 0) ? bih[c]        + bhh[c]
            : (g == 1) ? bih[1024 + c] + bhh[1024 + c]
            : (g == 2) ? bih[2048 + c] : bhh[2048 + c];
    bias[bi] = v;
  }
  if (gt < 1024) flag[gt] = 0;
}

// ---------------------------------------------------------------------------
// Persistent sequence kernel. grid 256 (rb = bid&7 -> XCD-local groups,
// j = bid>>3), block 512 = 8 waves: wave wv -> gate g=wv&3, K-half kh=wv>>2.
// Per wave: B = 32 cols x 512 k in regs (b[16][2] bf16x8 = 128 VGPR),
// acc 4x2 f32x4.  Per step: stage A slab (rb, 128KB) in 8 x 16KB dbuf chunks,
// 8 ds_read + 16 MFMA per chunk per wave; gate/K-half exchange via LDS G;
// fused GRU epilogue; h fp32 in regs; flag release/acquire per rb.
// ---------------------------------------------------------------------------
extern "C" __global__ void __launch_bounds__(512, 2)
gru_seq(char* __restrict__ A0p, char* __restrict__ A1p,
        const char* __restrict__ WB, const float* __restrict__ bias,
        const float* __restrict__ hidden, float* __restrict__ out,
        int* __restrict__ flag)
{
  __shared__ __align__(16) char lds[36864];   // A dbuf 2x16KB; G overlays [4][64][36] f32
  const int tid = threadIdx.x;
  const int wv = tid >> 6, ln = tid & 63;
  const int g = wv & 3, kh = wv >> 2;
  const int lrow = ln & 15, lq = ln >> 4;
  const int bid = blockIdx.x;
  const int rb = bid & 7, j = bid >> 3;

  // ---- B into registers (once) ----
  bf16x8 b[16][2];
  const char* wb = WB + (((j * 4 + g) * 32 + kh * 16) * 2) * 1024;
  #pragma unroll
  for (int cp = 0; cp < 16; cp++)
    #pragma unroll
    for (int n = 0; n < 2; n++)
      b[cp][n] = *(const bf16x8*)(wb + (cp * 2 + n) * 1024 + ln * 16);

  const float bv0 = (kh == 0) ? bias[g * 1024 + j * 32 + lrow]      : 0.f;
  const float bv1 = (kh == 0) ? bias[g * 1024 + j * 32 + 16 + lrow] : 0.f;

  // ---- per-thread epilogue geometry; h in regs ----
  const int erow = tid >> 3, ec0 = (tid & 7) * 4;     // 64 rows x 8 col-groups
  const int grow = rb * 64 + erow, gcol = j * 32 + ec0;
  f32x4 hreg = *(const f32x4*)(hidden + grow * 1024 + gcol);

  // Anext write address (element (grow, gcol..gcol+3) as next step's A frag)
  const int sA = j >> 4, cpA = (j & 15) >> 1, pA = j & 1, mA = erow >> 4;
  const int laneA = (erow & 15) + ((ec0 >> 3) & 3) * 16;
  const int aoff = (rb * 128 + ((cpA * 2 + sA) * 2 + pA) * 4 + mA) * 1024
                   + laneA * 16 + (ec0 & 7) * 2;

  float* G = (float*)lds;                      // gate exchange [4][64][36]
  const int abase_off = rb * 131072;

  for (int t = 0; t < 64; t++){
    const char* Acur = (t & 1) ? (const char*)A1p : (const char*)A0p;
    char* Anxt = (t & 1) ? A0p : A1p;
    if (t > 0){
      if (tid == 0){
        while (__hip_atomic_load(&flag[rb * 128 + t - 1],
                                 __ATOMIC_ACQUIRE, __HIP_MEMORY_SCOPE_AGENT) < 32)
          __builtin_amdgcn_s_sleep(2);
      }
      __syncthreads();
    }

    f32x4 acc[4][2];
    #pragma unroll
    for (int m = 0; m < 4; m++)
      #pragma unroll
      for (int n = 0; n < 2; n++)
        acc[m][n] = f32x4{0.f, 0.f, 0.f, 0.f};

    const char* abase = Acur + abase_off;
    // stage chunk 0 -> buf 0
    #pragma unroll
    for (int i = 0; i < 2; i++)
      __builtin_amdgcn_global_load_lds(GPTR(abase + (i * 512 + tid) * 16),
                                       LPTR(lds + (i * 512 + tid) * 16), 16, 0, 0);
    __syncthreads();

    #pragma unroll
    for (int c = 0; c < 8; c++){
      if (c < 7){
        #pragma unroll
        for (int i = 0; i < 2; i++)
          __builtin_amdgcn_global_load_lds(
              GPTR(abase + (c + 1) * 16384 + (i * 512 + tid) * 16),
              LPTR(lds + ((c + 1) & 1) * 16384 + (i * 512 + tid) * 16), 16, 0, 0);
      }
      #pragma unroll
      for (int p = 0; p < 2; p++){
        bf16x8 a[4];
        #pragma unroll
        for (int m = 0; m < 4; m++)
          a[m] = *(const bf16x8*)(lds + (c & 1) * 16384
                                  + ((kh * 2 + p) * 4 + m) * 1024 + ln * 16);
        #pragma unroll
        for (int m = 0; m < 4; m++)
          #pragma unroll
          for (int n = 0; n < 2; n++)
            acc[m][n] = __builtin_amdgcn_mfma_f32_16x16x32_bf16(
                            a[m], b[c * 2 + p][n], acc[m][n], 0, 0, 0);
      }
      __syncthreads();
    }

    // ---- gate exchange: kh=1 writes partials, kh=0 adds (+bias) ----
    if (kh == 1){
      #pragma unroll
      for (int m = 0; m < 4; m++)
        #pragma unroll
        for (int r4 = 0; r4 < 4; r4++){
          int row = m * 16 + lq * 4 + r4;
          G[g * 2304 + row * 36 + lrow]      = acc[m][0][r4];
          G[g * 2304 + row * 36 + 16 + lrow] = acc[m][1][r4];
        }
    }
    __syncthreads();
    if (kh == 0){
      #pragma unroll
      for (int m = 0; m < 4; m++)
        #pragma unroll
        for (int r4 = 0; r4 < 4; r4++){
          int row = m * 16 + lq * 4 + r4;
          G[g * 2304 + row * 36 + lrow]      += acc[m][0][r4] + bv0;
          G[g * 2304 + row * 36 + 16 + lrow] += acc[m][1][r4] + bv1;
        }
    }
    __syncthreads();

    // ---- fused GRU update (4 h-elems per thread) ----
    f32x4 vr = *(const f32x4*)(G + 0 * 2304 + erow * 36 + ec0);
    f32x4 vz = *(const f32x4*)(G + 1 * 2304 + erow * 36 + ec0);
    f32x4 vi = *(const f32x4*)(G + 2 * 2304 + erow * 36 + ec0);
    f32x4 vh = *(const f32x4*)(G + 3 * 2304 + erow * 36 + ec0);
    f32x4 vout; u16x4 hb;
    #pragma unroll
    for (int e = 0; e < 4; e++){
      float rr = 1.f / (1.f + __expf(-vr[e]));
      float zz = 1.f / (1.f + __expf(-vz[e]));
      float x  = vi[e] + rr * vh[e];
      float ex = __expf(-2.f * x);
      float nn = (1.f - ex) / (1.f + ex);
      float hn = nn + zz * (hreg[e] - nn);
      vout[e] = hn;
      hb[e] = f2bf(hn);
    }
    *(f32x4*)(out + (size_t)grow * 65536 + (size_t)t * 1024 + gcol) = vout;
    *(u16x4*)(Anxt + aoff) = hb;
    hreg = vout;

    __threadfence();
    __syncthreads();
    if (tid == 0)
      __hip_atomic_fetch_add(&flag[rb * 128 + t], 1,
                             __ATOMIC_RELEASE, __HIP_MEMORY_SCOPE_AGENT);
  }
}

// ---------------------------------------------------------------------------
extern "C" void kernel_launch(void* const* d_in, const int* in_sizes, int n_in,
                              void* d_out, int out_size, void* d_ws, size_t ws_size,
                              hipStream_t stream){
  const float* hidden = (const float*)d_in[0];
  const float* wih    = (const float*)d_in[1];
  const float* whh    = (const float*)d_in[2];
  const float* bih    = (const float*)d_in[3];
  const float* bhh    = (const float*)d_in[4];
  char*  ws   = (char*)d_ws;
  char*  WB   = ws + WB_OFF;
  float* bias = (float*)(ws + BIAS_OFF);
  char*  A0   = ws + A0_OFF;
  char*  A1   = ws + A1_OFF;
  int*   flag = (int*)(ws + FLAG_OFF);
  float* out  = (float*)d_out;

  hipLaunchKernelGGL(gru_weights, dim3(2048), dim3(256), 0, stream, wih, whh, WB);
  hipLaunchKernelGGL(gru_init,    dim3(256),  dim3(256), 0, stream,
                     hidden, bih, bhh, A0, bias, flag);
  hipLaunchKernelGGL(gru_seq,     dim3(256),  dim3(512), 0, stream,
                     A0, A1, (const char*)WB, (const float*)bias,
                     hidden, out, flag);
}

// Round 5
// 652.422 us; speedup vs baseline: 5.1609x; 5.1609x over previous
//
#include <hip/hip_runtime.h>

// DecoderGRU: h_{t+1} = GRUCell(h_t, h_t), 64 steps. Combined gates: r,z use
// (W_ih+W_hh); n keeps i_n,h_n -> one [512,1024]x[1024,4096] bf16 GEMM + fused
// GRU update per step. 64 step launches (grid-wide dep between steps).
// Step kernel: 256 blocks (1/CU), 512 thr = 8 waves = (gate g, K-half kh).
// Fragment-packed A/B in global: staging is linear global_load_lds (16B),
// ds_read_b128 lane-linear (conflict-free). 2-phase pipeline w/ raw barriers.

typedef float  f32x4 __attribute__((ext_vector_type(4)));
typedef __bf16 bf16x8 __attribute__((ext_vector_type(8)));
typedef unsigned short u16x8 __attribute__((ext_vector_type(8)));
typedef unsigned short u16x4 __attribute__((ext_vector_type(4)));

#define GPTR(p) ((const __attribute__((address_space(1))) unsigned int*)(p))
#define LPTR(p) ((__attribute__((address_space(3))) unsigned int*)(p))

// ws layout
#define WB_OFF   0u            // 8 MB frag-packed bf16 weights
#define BIAS_OFF 8388608u      // 16 KB combined biases [4][1024]
#define HWS_OFF  8404992u      // 2 MB fp32 h
#define A0_OFF   10502144u     // 1 MB frag-packed bf16 h (ping)
#define A1_OFF   11550720u     // 1 MB (pong)

__device__ __forceinline__ unsigned short f2bf(float f){
  unsigned int u = __builtin_bit_cast(unsigned int, f);
  u = (u + 0x7FFFu + ((u >> 16) & 1u)) >> 16;
  return (unsigned short)u;
}

// ---------------------------------------------------------------------------
// B layout: byte = j*262144 + c*32768 + fb*1024 + lane*16 + (k&7)*2
//   j=col>>5, c=k>>7, fb=(((k>>5)&3)*4+g)*2+((col>>4)&1),
//   lane=(col&15)+((k>>3)&3)*16.   gates: 0=r(+) 1=z(+) 2=i_n(ih) 3=h_n(hh)
// ---------------------------------------------------------------------------
extern "C" __global__ void gru_weights(const float* __restrict__ wih,
                                       const float* __restrict__ whh,
                                       char* __restrict__ WB){
  int gt  = blockIdx.x * 256 + threadIdx.x;   // 524288 threads
  int k0  = (gt & 127) << 3;                  // 8 k's per thread
  int gid = gt >> 7;
  int g   = gid >> 10, colg = gid & 1023;
  int srow = (g < 2) ? g * 1024 + colg : 2048 + colg;
  const float* pa = ((g == 3) ? whh : wih) + srow * 1024 + k0;
  f32x4 v0 = ((const f32x4*)pa)[0];
  f32x4 v1 = ((const f32x4*)pa)[1];
  if (g < 2){
    const float* pb = whh + srow * 1024 + k0;
    v0 += ((const f32x4*)pb)[0];
    v1 += ((const f32x4*)pb)[1];
  }
  u16x8 o;
  #pragma unroll
  for (int e = 0; e < 4; e++){ o[e] = f2bf(v0[e]); o[4 + e] = f2bf(v1[e]); }
  int cck = k0 >> 7;
  int fb  = (((k0 >> 5) & 3) * 4 + g) * 2 + ((colg >> 4) & 1);
  int lane= (colg & 15) + ((k0 >> 3) & 3) * 16;
  int addr= (colg >> 5) * 262144 + cck * 32768 + fb * 1024 + lane * 16;
  *(u16x8*)(WB + addr) = o;
}

// ---------------------------------------------------------------------------
// A layout: byte = (row>>6)*131072 + (hk>>7)*16384
//           + (((hk>>5)&3)*4 + ((row&63)>>4))*1024
//           + ((row&15)+((hk>>3)&3)*16)*16 + (hk&7)*2
// ---------------------------------------------------------------------------
extern "C" __global__ void gru_init(const float* __restrict__ hidden,
                                    const float* __restrict__ bih,
                                    const float* __restrict__ bhh,
                                    float* __restrict__ hws,
                                    char* __restrict__ A0,
                                    float* __restrict__ bias){
  int gt = blockIdx.x * 256 + threadIdx.x;    // 65536 threads, 8 elems each
  int e0 = gt * 8;
  int r  = e0 >> 10, c0 = e0 & 1023;
  f32x4 v0 = ((const f32x4*)(hidden + e0))[0];
  f32x4 v1 = ((const f32x4*)(hidden + e0))[1];
  ((f32x4*)(hws + e0))[0] = v0;
  ((f32x4*)(hws + e0))[1] = v1;
  u16x8 o;
  #pragma unroll
  for (int e = 0; e < 4; e++){ o[e] = f2bf(v0[e]); o[4 + e] = f2bf(v1[e]); }
  int addr = (r >> 6) * 131072 + (c0 >> 7) * 16384
           + (((c0 >> 5) & 3) * 4 + ((r & 63) >> 4)) * 1024
           + ((r & 15) + ((c0 >> 3) & 3) * 16) * 16;
  *(u16x8*)(A0 + addr) = o;
  if (blockIdx.x < 16){
    int bi = blockIdx.x * 256 + threadIdx.x;  // 4096 bias entries
    int g = bi >> 10, c = bi & 1023;
    float v = (g == 0) ? bih[c]        + bhh[c]
            : (g == 1) ? bih[1024 + c] + bhh[1024 + c]
            : (g == 2) ? bih[2048 + c] : bhh[2048 + c];
    bias[bi] = v;
  }
}

// ---------------------------------------------------------------------------
// Step kernel. LDS: A0@0 A1@16384 (16KB each), B0@32768 B1@65536 (32KB each).
// j=(bid&7)*4+((bid>>3)&3) (B-slab sharing is XCD-local), rb=bid>>5.
// Wave wv: g=wv&3, kh=wv>>2. Per chunk (BK=128): p in {0,1} k32-slices,
// a[4] x b[2] -> 16 MFMA. 2-phase: issue chunk c+1, compute c, vmcnt(0)+bar.
// ---------------------------------------------------------------------------
extern "C" __global__ void __launch_bounds__(512, 2)
gru_step(const char* __restrict__ Acur, char* __restrict__ Anext,
         float* __restrict__ hws, const char* __restrict__ WB,
         const float* __restrict__ bias, float* __restrict__ out, int t)
{
  __shared__ __align__(16) char lds[98304];
  const int tid = threadIdx.x;
  const int wv = tid >> 6, ln = tid & 63;
  const int g = wv & 3, kh = wv >> 2;
  const int lrow = ln & 15, lq = ln >> 4;
  const int bid = blockIdx.x;
  const int j  = (bid & 7) * 4 + ((bid >> 3) & 3);
  const int rb = bid >> 5;
  const int abase = rb * 131072;
  const int bbase = j * 262144;

  f32x4 acc[4][2];
  #pragma unroll
  for (int m = 0; m < 4; m++)
    #pragma unroll
    for (int n = 0; n < 2; n++) acc[m][n] = f32x4{0.f,0.f,0.f,0.f};

  const float bv0 = (kh == 0) ? bias[g * 1024 + j * 32 + lrow]      : 0.f;
  const float bv1 = (kh == 0) ? bias[g * 1024 + j * 32 + 16 + lrow] : 0.f;

#define STAGE(cc, buf) do { \
    _Pragma("unroll") \
    for (int i = 0; i < 2; i++) \
      __builtin_amdgcn_global_load_lds( \
          GPTR(Acur + abase + (cc) * 16384 + tid * 16 + i * 8192), \
          LPTR(lds + (buf) * 16384 + tid * 16 + i * 8192), 16, 0, 0); \
    _Pragma("unroll") \
    for (int i = 0; i < 4; i++) \
      __builtin_amdgcn_global_load_lds( \
          GPTR(WB + bbase + (cc) * 32768 + tid * 16 + i * 8192), \
          LPTR(lds + 32768 + (buf) * 32768 + tid * 16 + i * 8192), 16, 0, 0); \
  } while (0)

  STAGE(0, 0);
  asm volatile("s_waitcnt vmcnt(0)" ::: "memory");
  __builtin_amdgcn_s_barrier();

  #pragma unroll
  for (int c = 0; c < 8; c++){
    if (c < 7) STAGE(c + 1, (c + 1) & 1);
    #pragma unroll
    for (int p = 0; p < 2; p++){
      const int ks = kh * 2 + p;
      bf16x8 a[4], b[2];
      #pragma unroll
      for (int m = 0; m < 4; m++)
        a[m] = *(const bf16x8*)(lds + (c & 1) * 16384 + (ks * 4 + m) * 1024 + ln * 16);
      #pragma unroll
      for (int n = 0; n < 2; n++)
        b[n] = *(const bf16x8*)(lds + 32768 + (c & 1) * 32768
                                + ((ks * 4 + g) * 2 + n) * 1024 + ln * 16);
      #pragma unroll
      for (int m = 0; m < 4; m++)
        #pragma unroll
        for (int n = 0; n < 2; n++)
          acc[m][n] = __builtin_amdgcn_mfma_f32_16x16x32_bf16(a[m], b[n], acc[m][n], 0, 0, 0);
    }
    asm volatile("s_waitcnt vmcnt(0)" ::: "memory");
    __builtin_amdgcn_s_barrier();
  }
#undef STAGE

  // ---- gate exchange: G[4 gates][64 rows][36], kh=1 writes, kh=0 adds ----
  float* G = (float*)lds;
  if (kh == 1){
    #pragma unroll
    for (int m = 0; m < 4; m++)
      #pragma unroll
      for (int r4 = 0; r4 < 4; r4++){
        int row = m * 16 + lq * 4 + r4;
        G[g * 2304 + row * 36 + lrow]      = acc[m][0][r4];
        G[g * 2304 + row * 36 + 16 + lrow] = acc[m][1][r4];
      }
  }
  __syncthreads();
  if (kh == 0){
    #pragma unroll
    for (int m = 0; m < 4; m++)
      #pragma unroll
      for (int r4 = 0; r4 < 4; r4++){
        int row = m * 16 + lq * 4 + r4;
        G[g * 2304 + row * 36 + lrow]      += acc[m][0][r4] + bv0;
        G[g * 2304 + row * 36 + 16 + lrow] += acc[m][1][r4] + bv1;
      }
  }
  __syncthreads();

  // ---- fused GRU update: 512 threads x (1 row, 4 cols) ----
  const int erow = tid >> 3, ec0 = (tid & 7) * 4;
  const int base = erow * 36 + ec0;
  f32x4 vr = *(const f32x4*)(G + base);
  f32x4 vz = *(const f32x4*)(G + 2304 + base);
  f32x4 vi = *(const f32x4*)(G + 4608 + base);
  f32x4 vh = *(const f32x4*)(G + 6912 + base);
  const int grow = rb * 64 + erow;
  const int gcol = j * 32 + ec0;
  f32x4 hold = *(const f32x4*)(hws + grow * 1024 + gcol);
  f32x4 vout; u16x4 hb;
  #pragma unroll
  for (int e = 0; e < 4; e++){
    float rr = 1.f / (1.f + __expf(-vr[e]));
    float zz = 1.f / (1.f + __expf(-vz[e]));
    float x  = vi[e] + rr * vh[e];
    float ex = __expf(-2.f * x);
    float nn = (1.f - ex) / (1.f + ex);
    float hn = nn + zz * (hold[e] - nn);
    vout[e] = hn;
    hb[e] = f2bf(hn);
  }
  *(f32x4*)(out + (size_t)grow * 65536 + (size_t)t * 1024 + gcol) = vout;
  *(f32x4*)(hws + grow * 1024 + gcol) = vout;
  // A-next frag-packed write (4 bf16 = 8B, within one lane slot)
  int aaddr = rb * 131072 + (j >> 2) * 16384
            + ((j & 3) * 4 + (erow >> 4)) * 1024
            + ((erow & 15) + ((ec0 >> 3) & 3) * 16) * 16 + (ec0 & 7) * 2;
  *(u16x4*)(Anext + aaddr) = hb;
}

// ---------------------------------------------------------------------------
extern "C" void kernel_launch(void* const* d_in, const int* in_sizes, int n_in,
                              void* d_out, int out_size, void* d_ws, size_t ws_size,
                              hipStream_t stream){
  const float* hidden = (const float*)d_in[0];
  const float* wih    = (const float*)d_in[1];
  const float* whh    = (const float*)d_in[2];
  const float* bih    = (const float*)d_in[3];
  const float* bhh    = (const float*)d_in[4];
  char*  ws   = (char*)d_ws;
  char*  WB   = ws + WB_OFF;
  float* bias = (float*)(ws + BIAS_OFF);
  float* hws  = (float*)(ws + HWS_OFF);
  char*  A0   = ws + A0_OFF;
  char*  A1   = ws + A1_OFF;
  float* out  = (float*)d_out;

  hipLaunchKernelGGL(gru_weights, dim3(2048), dim3(256), 0, stream, wih, whh, WB);
  hipLaunchKernelGGL(gru_init,    dim3(256),  dim3(256), 0, stream,
                     hidden, bih, bhh, hws, A0, bias);
  for (int t = 0; t < 64; t++){
    char* Asrc = (t & 1) ? A1 : A0;
    char* Adst = (t & 1) ? A0 : A1;
    hipLaunchKernelGGL(gru_step, dim3(256), dim3(512), 0, stream,
                       (const char*)Asrc, Adst, hws,
                       (const char*)WB, (const float*)bias, out, t);
  }
}